// Round 1
// baseline (141.572 us; speedup 1.0000x reference)
//
#include <hip/hip_runtime.h>
#include <hip/hip_bf16.h>

#define BSZ  16
#define NTOK 128
#define CHN  512
#define KTOT 1024
#define EPSV 1e-5f

typedef __attribute__((ext_vector_type(8))) short bf16x8;
typedef __attribute__((ext_vector_type(4))) float f32x4;

union BfPack4 { ushort4 u; __hip_bfloat16 h[4]; };

// ---------------------------------------------------------------------------
// K1: per block: batch b, rows i0..i0+3.
//   phase 0: convert one Wf row (row = blockIdx.x) to bf16 in ws
//   phase 1: score row segments via LDS-staged transposed x tiles
//   softmax (shift-invariant: only scale s and diagonal -1e8 matter)
//   phase 2: xnb = W @ x[b], write bf16 [x | xnb] rows into ws
// ---------------------------------------------------------------------------
__global__ __launch_bounds__(128)
void k1_score_softmax_xnb(const float* __restrict__ xg,
                          const float* __restrict__ wde,     // conv_e_w (first 512 used)
                          const float* __restrict__ bn_e_g,
                          const float* __restrict__ bn_e_v,
                          const float* __restrict__ wf,      // conv_f_w [512][1024]
                          __hip_bfloat16* __restrict__ hb,   // [2048][1024]
                          __hip_bfloat16* __restrict__ wfb)  // [512][1024]
{
    __shared__ float xs[64][129];   // transposed tile: xs[c][j]
    __shared__ float wrow[4][132];  // softmax weights, 4 rows x 128 j
    __shared__ float red[2][8];     // cross-wave reduction

    const int t   = threadIdx.x;
    const int blk = blockIdx.x;
    const int b   = blk >> 5;
    const int i0  = (blk & 31) << 2;
    const float* __restrict__ xb = xg + (size_t)b * NTOK * CHN;

    // ---- phase 0: Wf row -> bf16 (blk in [0,512)) ----
    {
        const float* wr = wf + (size_t)blk * KTOT;
        float4 u0 = *(const float4*)&wr[t * 8];
        float4 u1 = *(const float4*)&wr[t * 8 + 4];
        BfPack4 p0, p1;
        p0.h[0] = __float2bfloat16(u0.x); p0.h[1] = __float2bfloat16(u0.y);
        p0.h[2] = __float2bfloat16(u0.z); p0.h[3] = __float2bfloat16(u0.w);
        p1.h[0] = __float2bfloat16(u1.x); p1.h[1] = __float2bfloat16(u1.y);
        p1.h[2] = __float2bfloat16(u1.z); p1.h[3] = __float2bfloat16(u1.w);
        *(ushort4*)&wfb[(size_t)blk * KTOT + t * 8]     = p0.u;
        *(ushort4*)&wfb[(size_t)blk * KTOT + t * 8 + 4] = p1.u;
    }

    // ---- phase 1: raw scores; thread t owns column j = t ----
    float acc[4] = {0.f, 0.f, 0.f, 0.f};

    for (int c0 = 0; c0 < CHN; c0 += 64) {
        // stage x[b, all j, c0..c0+63] transposed into xs[c][j]
        #pragma unroll
        for (int p = 0; p < 16; ++p) {
            const int j  = p * 8 + (t >> 4);
            const int c4 = (t & 15) * 4;
            float4 v = *(const float4*)&xb[(size_t)j * CHN + c0 + c4];
            xs[c4 + 0][j] = v.x; xs[c4 + 1][j] = v.y;
            xs[c4 + 2][j] = v.z; xs[c4 + 3][j] = v.w;
        }
        __syncthreads();

        #pragma unroll 4
        for (int g4 = 0; g4 < 16; ++g4) {
            const int c = c0 + g4 * 4;
            const float4 wdv = *(const float4*)&wde[c];                         // uniform -> s_load
            const float4 xi0 = *(const float4*)&xb[(size_t)(i0 + 0) * CHN + c]; // uniform
            const float4 xi1 = *(const float4*)&xb[(size_t)(i0 + 1) * CHN + c];
            const float4 xi2 = *(const float4*)&xb[(size_t)(i0 + 2) * CHN + c];
            const float4 xi3 = *(const float4*)&xb[(size_t)(i0 + 3) * CHN + c];
            const int cl = g4 * 4;
            const float xj0 = xs[cl + 0][t];
            const float xj1 = xs[cl + 1][t];
            const float xj2 = xs[cl + 2][t];
            const float xj3 = xs[cl + 3][t];
            acc[0] += fabsf(xi0.x - xj0) * wdv.x + fabsf(xi0.y - xj1) * wdv.y
                    + fabsf(xi0.z - xj2) * wdv.z + fabsf(xi0.w - xj3) * wdv.w;
            acc[1] += fabsf(xi1.x - xj0) * wdv.x + fabsf(xi1.y - xj1) * wdv.y
                    + fabsf(xi1.z - xj2) * wdv.z + fabsf(xi1.w - xj3) * wdv.w;
            acc[2] += fabsf(xi2.x - xj0) * wdv.x + fabsf(xi2.y - xj1) * wdv.y
                    + fabsf(xi2.z - xj2) * wdv.z + fabsf(xi2.w - xj3) * wdv.w;
            acc[3] += fabsf(xi3.x - xj0) * wdv.x + fabsf(xi3.y - xj1) * wdv.y
                    + fabsf(xi3.z - xj2) * wdv.z + fabsf(xi3.w - xj3) * wdv.w;
        }
        __syncthreads();
    }

    // ---- softmax over j (128 threads = 2 waves) ----
    const float sc = bn_e_g[0] * rsqrtf(bn_e_v[0] + EPSV);
    float logit[4];
    #pragma unroll
    for (int ti = 0; ti < 4; ++ti) {
        logit[ti] = acc[ti] * sc;
        if (t == i0 + ti) logit[ti] -= 1e8f;   // diagonal mask
    }
    const int wid = t >> 6, lane = t & 63;
    float mx[4];
    #pragma unroll
    for (int ti = 0; ti < 4; ++ti) {
        float v = logit[ti];
        #pragma unroll
        for (int off = 32; off > 0; off >>= 1) v = fmaxf(v, __shfl_xor(v, off));
        mx[ti] = v;
    }
    if (lane == 0) {
        red[wid][0] = mx[0]; red[wid][1] = mx[1];
        red[wid][2] = mx[2]; red[wid][3] = mx[3];
    }
    __syncthreads();
    float pe[4], sm[4];
    #pragma unroll
    for (int ti = 0; ti < 4; ++ti) {
        const float M = fmaxf(red[0][ti], red[1][ti]);
        pe[ti] = __expf(logit[ti] - M);
        float v = pe[ti];
        #pragma unroll
        for (int off = 32; off > 0; off >>= 1) v += __shfl_xor(v, off);
        sm[ti] = v;
    }
    if (lane == 0) {
        red[wid][4] = sm[0]; red[wid][5] = sm[1];
        red[wid][6] = sm[2]; red[wid][7] = sm[3];
    }
    __syncthreads();
    #pragma unroll
    for (int ti = 0; ti < 4; ++ti) {
        const float S = red[0][4 + ti] + red[1][4 + ti];
        wrow[ti][t] = pe[ti] / S;
    }
    __syncthreads();

    // ---- phase 2: xnb rows + bf16 conversion of [x | xnb] ----
    const int c4 = t << 2;
    float4 av[4];
    #pragma unroll
    for (int ti = 0; ti < 4; ++ti) { av[ti].x = av[ti].y = av[ti].z = av[ti].w = 0.f; }

    for (int j = 0; j < NTOK; ++j) {
        const float4 xj = *(const float4*)&xb[(size_t)j * CHN + c4];
        const float w0 = wrow[0][j], w1 = wrow[1][j], w2 = wrow[2][j], w3 = wrow[3][j];
        av[0].x += w0 * xj.x; av[0].y += w0 * xj.y; av[0].z += w0 * xj.z; av[0].w += w0 * xj.w;
        av[1].x += w1 * xj.x; av[1].y += w1 * xj.y; av[1].z += w1 * xj.z; av[1].w += w1 * xj.w;
        av[2].x += w2 * xj.x; av[2].y += w2 * xj.y; av[2].z += w2 * xj.z; av[2].w += w2 * xj.w;
        av[3].x += w3 * xj.x; av[3].y += w3 * xj.y; av[3].z += w3 * xj.z; av[3].w += w3 * xj.w;
    }

    #pragma unroll
    for (int ti = 0; ti < 4; ++ti) {
        const size_t row = (size_t)(b * NTOK + i0 + ti);
        BfPack4 pk;
        pk.h[0] = __float2bfloat16(av[ti].x); pk.h[1] = __float2bfloat16(av[ti].y);
        pk.h[2] = __float2bfloat16(av[ti].z); pk.h[3] = __float2bfloat16(av[ti].w);
        *(ushort4*)&hb[row * KTOT + CHN + c4] = pk.u;
        const float4 xv = *(const float4*)&xb[(size_t)(i0 + ti) * CHN + c4];
        pk.h[0] = __float2bfloat16(xv.x); pk.h[1] = __float2bfloat16(xv.y);
        pk.h[2] = __float2bfloat16(xv.z); pk.h[3] = __float2bfloat16(xv.w);
        *(ushort4*)&hb[row * KTOT + c4] = pk.u;
    }
}

// ---------------------------------------------------------------------------
// K2: out = relu(BN([x|xnb] @ Wf^T + bias)) via bf16 MFMA, direct global frags.
// 256 blocks (32 row-tiles x 8 col-tiles of 64x64), 4 waves of 2x2 16x16 tiles.
// ---------------------------------------------------------------------------
__global__ __launch_bounds__(256)
void k2_gemm_bn_relu(const __hip_bfloat16* __restrict__ hbp,
                     const __hip_bfloat16* __restrict__ wfbp,
                     const float* __restrict__ fb,
                     const float* __restrict__ gg,
                     const float* __restrict__ bb,
                     const float* __restrict__ mm,
                     const float* __restrict__ vv,
                     float* __restrict__ out)
{
    const int blk  = blockIdx.x;
    const int r0   = (blk >> 3) << 6;
    const int c0   = (blk & 7) << 6;
    const int t    = threadIdx.x;
    const int w    = t >> 6;
    const int lane = t & 63;
    const int wm   = w & 1;
    const int wn   = w >> 1;
    const int m16  = lane & 15;
    const int q    = lane >> 4;

    const short* A0 = (const short*)hbp  + (size_t)(r0 + wm * 32 + m16) * KTOT + q * 8;
    const short* B0 = (const short*)wfbp + (size_t)(c0 + wn * 32 + m16) * KTOT + q * 8;

    f32x4 acc00 = {0.f, 0.f, 0.f, 0.f};
    f32x4 acc01 = acc00, acc10 = acc00, acc11 = acc00;

    #pragma unroll 4
    for (int k0 = 0; k0 < KTOT; k0 += 32) {
        const bf16x8 aA = *(const bf16x8*)(A0 + k0);
        const bf16x8 aB = *(const bf16x8*)(A0 + 16 * KTOT + k0);
        const bf16x8 bA = *(const bf16x8*)(B0 + k0);
        const bf16x8 bB = *(const bf16x8*)(B0 + 16 * KTOT + k0);
        acc00 = __builtin_amdgcn_mfma_f32_16x16x32_bf16(aA, bA, acc00, 0, 0, 0);
        acc01 = __builtin_amdgcn_mfma_f32_16x16x32_bf16(aA, bB, acc01, 0, 0, 0);
        acc10 = __builtin_amdgcn_mfma_f32_16x16x32_bf16(aB, bA, acc10, 0, 0, 0);
        acc11 = __builtin_amdgcn_mfma_f32_16x16x32_bf16(aB, bB, acc11, 0, 0, 0);
    }

    // epilogue: C/D layout col = lane&15, row = (lane>>4)*4 + reg  [m89-verified]
    #pragma unroll
    for (int ni = 0; ni < 2; ++ni) {
        const int c = c0 + wn * 32 + ni * 16 + m16;
        const float gf = gg[c] * rsqrtf(vv[c] + EPSV);
        const float ad = fb[c] - mm[c];
        const float bv = bb[c];
        const f32x4 acr0 = ni ? acc01 : acc00;
        const f32x4 acr1 = ni ? acc11 : acc10;
        #pragma unroll
        for (int r2 = 0; r2 < 4; ++r2) {
            int row = r0 + wm * 32 + q * 4 + r2;
            float val = (acr0[r2] + ad) * gf + bv;
            out[(size_t)row * CHN + c] = fmaxf(val, 0.f);
            row += 16;
            val = (acr1[r2] + ad) * gf + bv;
            out[(size_t)row * CHN + c] = fmaxf(val, 0.f);
        }
    }
}

extern "C" void kernel_launch(void* const* d_in, const int* in_sizes, int n_in,
                              void* d_out, int out_size, void* d_ws, size_t ws_size,
                              hipStream_t stream) {
    const float* x        = (const float*)d_in[0];
    // d_in[1] = y          : unused (softmax shift-invariance)
    const float* conv_e_w = (const float*)d_in[2];
    // d_in[3] = conv_e_b   : unused (shift)
    const float* bn_e_g   = (const float*)d_in[4];
    // d_in[5] = bn_e_b     : unused (shift)
    // d_in[6] = bn_e_m     : unused (shift)
    const float* bn_e_v   = (const float*)d_in[7];
    const float* conv_f_w = (const float*)d_in[8];
    const float* conv_f_b = (const float*)d_in[9];
    const float* bn_f_g   = (const float*)d_in[10];
    const float* bn_f_b   = (const float*)d_in[11];
    const float* bn_f_m   = (const float*)d_in[12];
    const float* bn_f_v   = (const float*)d_in[13];
    float* out = (float*)d_out;

    __hip_bfloat16* hb  = (__hip_bfloat16*)d_ws;              // 2048*1024 bf16 = 4 MB
    __hip_bfloat16* wfb = hb + (size_t)2048 * 1024;           // 512*1024 bf16  = 1 MB

    k1_score_softmax_xnb<<<512, 128, 0, stream>>>(x, conv_e_w, bn_e_g, bn_e_v,
                                                  conv_f_w, hb, wfb);
    k2_gemm_bn_relu<<<256, 256, 0, stream>>>(hb, wfb, conv_f_b, bn_f_g, bn_f_b,
                                             bn_f_m, bn_f_v, out);
}